// Round 2
// baseline (232.192 us; speedup 1.0000x reference)
//
#include <hip/hip_runtime.h>
#include <math.h>

// Problem constants (from reference): B=8, S=4096, D=1024, H=12.
#define D_DIM 1024
#define S_DIM 4096

#define TWO_PI     6.283185307179586476925286766559
#define INV_TWO_PI 0.159154943091895335768883763373

// ---------------------------------------------------------------------------
// Kernel 1: wave[t] = (1/H) * sum_i amp[i] * sin(2*pi*f[i]*(time + t/S))
// Phase computed in double (exact at |ph|~3e4), range-reduced to [-pi,pi]
// with 4 cheap DP ops, then fp32 sinf on the small argument (fast path —
// avoids the DP Payne-Hanek slow path that made round 1's prologue
// latency-bound at 64 waves on 256 CUs).
// ---------------------------------------------------------------------------
__global__ void ResonanceField_wave_kernel(const float* __restrict__ freq,
                                           const float* __restrict__ amp,
                                           const float* __restrict__ time_p,
                                           float* __restrict__ wave,
                                           int H, int S) {
    int t = blockIdx.x * blockDim.x + threadIdx.x;
    if (t >= S) return;
    double tf = (double)time_p[0] + (double)t / (double)S;
    double acc = 0.0;
    for (int i = 0; i < H; ++i) {
        double ph = TWO_PI * (double)freq[i] * tf;
        double r  = ph - TWO_PI * rint(ph * INV_TWO_PI);   // exact-ish reduction
        acc += (double)amp[i] * (double)sinf((float)r);     // small-arg fast path
    }
    wave[t] = (float)(acc / (double)H);
}

// ---------------------------------------------------------------------------
// Kernel 2: out[b,t,d] = x[b,t,d] * wave[t]
// One block per (b,t) row: 256 threads x float4 = 1024 floats = one row of D.
// t = blockIdx.x & (S-1) is wave-uniform -> wave[t] broadcast from one line.
// Pure streaming: 16 B/lane coalesced load + store. This is the roofline leg.
// ---------------------------------------------------------------------------
__global__ void ResonanceField_scale_kernel(const float4* __restrict__ x,
                                            const float* __restrict__ wave,
                                            float4* __restrict__ out) {
    const int t = blockIdx.x & (S_DIM - 1);
    const float w = wave[t];
    const size_t idx = (size_t)blockIdx.x * blockDim.x + threadIdx.x;
    float4 v = x[idx];
    v.x *= w; v.y *= w; v.z *= w; v.w *= w;
    out[idx] = v;
}

// ---------------------------------------------------------------------------
// Fallback (only if ws_size < S*4 bytes): fused, same fast-reduction math,
// redundantly per thread. Not expected to be used (ws_size is ample).
// ---------------------------------------------------------------------------
__global__ void ResonanceField_fused_kernel(const float4* __restrict__ x,
                                            const float* __restrict__ freq,
                                            const float* __restrict__ amp,
                                            const float* __restrict__ time_p,
                                            float4* __restrict__ out,
                                            int H) {
    const int t = blockIdx.x & (S_DIM - 1);
    const double tf = (double)time_p[0] + (double)t * (1.0 / (double)S_DIM);
    double acc = 0.0;
    for (int i = 0; i < H; ++i) {
        double ph = TWO_PI * (double)freq[i] * tf;
        double r  = ph - TWO_PI * rint(ph * INV_TWO_PI);
        acc += (double)amp[i] * (double)sinf((float)r);
    }
    const float w = (float)(acc / (double)H);
    const size_t idx = (size_t)blockIdx.x * blockDim.x + threadIdx.x;
    float4 v = x[idx];
    v.x *= w; v.y *= w; v.z *= w; v.w *= w;
    out[idx] = v;
}

extern "C" void kernel_launch(void* const* d_in, const int* in_sizes, int n_in,
                              void* d_out, int out_size, void* d_ws, size_t ws_size,
                              hipStream_t stream) {
    const float* x      = (const float*)d_in[0];
    const float* freq   = (const float*)d_in[1];
    const float* amp    = (const float*)d_in[2];
    const float* time_p = (const float*)d_in[3];
    float* out = (float*)d_out;

    const int H = in_sizes[1];                        // 12
    const long long total = (long long)in_sizes[0];   // B*S*D = 33554432
    const int rows = (int)(total / D_DIM);            // B*S = 32768 blocks
    const int threads = 256;                          // 256 * float4 = 1024 = D

    if (ws_size >= (size_t)S_DIM * sizeof(float)) {
        float* wave = (float*)d_ws;
        ResonanceField_wave_kernel<<<(S_DIM + threads - 1) / threads, threads, 0, stream>>>(
            freq, amp, time_p, wave, H, S_DIM);
        ResonanceField_scale_kernel<<<rows, threads, 0, stream>>>(
            (const float4*)x, wave, (float4*)out);
    } else {
        ResonanceField_fused_kernel<<<rows, threads, 0, stream>>>(
            (const float4*)x, freq, amp, time_p, (float4*)out, H);
    }
}

// Round 4
// 229.030 us; speedup vs baseline: 1.0138x; 1.0138x over previous
//
#include <hip/hip_runtime.h>
#include <math.h>

// Problem constants (from reference): B=8, S=4096, D=1024, H=12.
#define D_DIM 1024
#define S_DIM 4096
#define F4_PER_ROW (D_DIM / 4)     // 256 float4 per (b,t) row
#define ROWS_PER_BLOCK 4

#define TWO_PI     6.283185307179586476925286766559
#define INV_TWO_PI 0.159154943091895335768883763373

// Native clang vector type — required by __builtin_nontemporal_load/store
// (HIP_vector_type<float,4> is a struct and is rejected).
typedef float vfloat4 __attribute__((ext_vector_type(4)));

// ---------------------------------------------------------------------------
// Kernel 1: wave[t] = (1/H) * sum_i amp[i] * sin(2*pi*f[i]*(time + t/S))
// DP phase + cheap DP range reduction + fp32 sinf. ~3 us, off critical path.
// ---------------------------------------------------------------------------
__global__ void ResonanceField_wave_kernel(const float* __restrict__ freq,
                                           const float* __restrict__ amp,
                                           const float* __restrict__ time_p,
                                           float* __restrict__ wave,
                                           int H, int S) {
    int t = blockIdx.x * blockDim.x + threadIdx.x;
    if (t >= S) return;
    double tf = (double)time_p[0] + (double)t / (double)S;
    double acc = 0.0;
    for (int i = 0; i < H; ++i) {
        double ph = TWO_PI * (double)freq[i] * tf;
        double r  = ph - TWO_PI * rint(ph * INV_TWO_PI);   // |r| <= pi, ~1e-12 exact
        acc += (double)amp[i] * (double)sinf((float)r);
    }
    wave[t] = (float)(acc / (double)H);
}

// ---------------------------------------------------------------------------
// Kernel 2: out[b,t,d] = x[b,t,d] * wave[t]
// 4 rows per block, 256 threads, 4 independent 16B ld/st pairs per thread
// (4 outstanding dwordx4 per wave -> better MLP). Nontemporal (nt) on the
// streaming x/out traffic: read-once / write-once, skip L2 retention.
// ---------------------------------------------------------------------------
__global__ void __launch_bounds__(256)
ResonanceField_scale_kernel(const vfloat4* __restrict__ x,
                            const float* __restrict__ wave,
                            vfloat4* __restrict__ out) {
    const int row0 = blockIdx.x * ROWS_PER_BLOCK;
    const int tid  = threadIdx.x;

    float   w[ROWS_PER_BLOCK];
    size_t  idx[ROWS_PER_BLOCK];
    vfloat4 v[ROWS_PER_BLOCK];

#pragma unroll
    for (int r = 0; r < ROWS_PER_BLOCK; ++r) {
        const int row = row0 + r;
        w[r]   = wave[row & (S_DIM - 1)];
        idx[r] = (size_t)row * F4_PER_ROW + tid;
        v[r]   = __builtin_nontemporal_load(&x[idx[r]]);
    }
#pragma unroll
    for (int r = 0; r < ROWS_PER_BLOCK; ++r) {
        v[r] *= w[r];
        __builtin_nontemporal_store(v[r], &out[idx[r]]);
    }
}

// ---------------------------------------------------------------------------
// Fallback (only if ws_size < S*4 bytes): fused single-row kernel.
// ---------------------------------------------------------------------------
__global__ void ResonanceField_fused_kernel(const vfloat4* __restrict__ x,
                                            const float* __restrict__ freq,
                                            const float* __restrict__ amp,
                                            const float* __restrict__ time_p,
                                            vfloat4* __restrict__ out,
                                            int H) {
    const int t = blockIdx.x & (S_DIM - 1);
    const double tf = (double)time_p[0] + (double)t * (1.0 / (double)S_DIM);
    double acc = 0.0;
    for (int i = 0; i < H; ++i) {
        double ph = TWO_PI * (double)freq[i] * tf;
        double r  = ph - TWO_PI * rint(ph * INV_TWO_PI);
        acc += (double)amp[i] * (double)sinf((float)r);
    }
    const float w = (float)(acc / (double)H);
    const size_t idx = (size_t)blockIdx.x * blockDim.x + threadIdx.x;
    vfloat4 v = x[idx];
    v *= w;
    out[idx] = v;
}

extern "C" void kernel_launch(void* const* d_in, const int* in_sizes, int n_in,
                              void* d_out, int out_size, void* d_ws, size_t ws_size,
                              hipStream_t stream) {
    const float* x      = (const float*)d_in[0];
    const float* freq   = (const float*)d_in[1];
    const float* amp    = (const float*)d_in[2];
    const float* time_p = (const float*)d_in[3];
    float* out = (float*)d_out;

    const int H = in_sizes[1];                        // 12
    const long long total = (long long)in_sizes[0];   // B*S*D = 33554432
    const int rows = (int)(total / D_DIM);            // B*S = 32768 rows
    const int threads = 256;

    if (ws_size >= (size_t)S_DIM * sizeof(float)) {
        float* wave = (float*)d_ws;
        ResonanceField_wave_kernel<<<(S_DIM + threads - 1) / threads, threads, 0, stream>>>(
            freq, amp, time_p, wave, H, S_DIM);
        ResonanceField_scale_kernel<<<rows / ROWS_PER_BLOCK, threads, 0, stream>>>(
            (const vfloat4*)x, wave, (vfloat4*)out);
    } else {
        ResonanceField_fused_kernel<<<rows, threads, 0, stream>>>(
            (const vfloat4*)x, freq, amp, time_p, (vfloat4*)out, H);
    }
}